// Round 4
// baseline (155.257 us; speedup 1.0000x reference)
//
#include <hip/hip_runtime.h>
#include <math.h>

// Round 15: 5-barrier fused pipeline, fixed-point bucket exp-sums.
// Round-14 evidence: kernel 72.8us, VALUBusy 8.3% (~6us VALU) -> ~20us work,
// ~50us in 6 barriers (~8us each). Changes:
//   - P4 (se chunk scan) ELIMINATED: cross-bucket exp term is per-BUCKET, not
//     per-position. P1 uses ONE u64 atomic per element: (1<<40)|round(e*2^24).
//     High bits = count ticket (deterministic), low 40 = fixed-point exp sum
//     (integer-exact -> deterministic, unlike float atomics).
//   - P2a/P2b suffix-scan {count,expsum} over DESCENDING buckets (direct
//     accumulation: cross==0 exactly for top bucket, no cancellation).
//     Epack[b] = {sfxCnt, crossBits, cnt, 0} -> one 16B load in P5.
//   - NREP=1 (u64/bucket): memset 8MB->4MB, P2a reads halve. Within-bucket
//     order still resolved exactly in P5 (order-invariant tie-break).
//   - Hj rank-match bitmap (32KB, built in P1): 1 hot load replaces 13-step
//     binsearch; binsearch only on ~3% hits.
//   - gbar poll s_sleep(8)->s_sleep(1).
// Barriers: 5 (was 6). All cross-barrier producer writes remain agent-scope
// relaxed stores (sc1); consumers plain-load first-touch-after-write.

#define BSHIFT 12
#define NBUCK (1 << 19)          // key>>12 of positive floats
#define BLK 256
#define NC1 32
#define M40 ((1ull << 40) - 1)

#define STORE_U32(p, v) __hip_atomic_store((p), (v), __ATOMIC_RELAXED, __HIP_MEMORY_SCOPE_AGENT)
#define STORE_F32(p, v) __hip_atomic_store((p), (v), __ATOMIC_RELAXED, __HIP_MEMORY_SCOPE_AGENT)
#define STORE_U64(p, v) __hip_atomic_store((unsigned long long*)(p), (v), __ATOMIC_RELAXED, __HIP_MEMORY_SCOPE_AGENT)

// bar u32 layout: c1[i] @ i*16 (i<32, 64B pad); c2 @ 512; genCopy[i] @ 544+i*16.
// Monotonic, zeroed by host memset each launch (workspace is re-poisoned).
template <int GRID>
__device__ __forceinline__ void gbar(unsigned* bar, unsigned gv) {
  __syncthreads();   // all waves done; compiler drains vm/lgkm before s_barrier
  if (threadIdx.x == 0) {
    constexpr unsigned BPC = GRID / NC1;
    const unsigned grp = blockIdx.x & (NC1 - 1);
    unsigned a = __hip_atomic_fetch_add(bar + grp * 16, 1u,
                                        __ATOMIC_RELAXED, __HIP_MEMORY_SCOPE_AGENT);
    if (a == gv * BPC - 1u) {
      unsigned b = __hip_atomic_fetch_add(bar + 512, 1u,
                                          __ATOMIC_RELAXED, __HIP_MEMORY_SCOPE_AGENT);
      if (b == gv * NC1 - 1u) {
        #pragma unroll
        for (int i = 0; i < NC1; ++i)
          STORE_U32(bar + 544 + i * 16, gv);   // broadcast release
      }
    }
    int guard = 0;
    while (__hip_atomic_load(bar + 544 + grp * 16, __ATOMIC_RELAXED,
                             __HIP_MEMORY_SCOPE_AGENT) < gv) {
      __builtin_amdgcn_s_sleep(1);
      if (++guard > 2000000) break;   // failsafe: never hang the queue
    }
  }
  __syncthreads();
}

template <int GRID>
__global__ void __launch_bounds__(BLK, 4)
k_fused(const float2* __restrict__ yt0, const float* __restrict__ yp0,
        const float* __restrict__ yp1, const int* __restrict__ Hj,
        const float* __restrict__ lv, int n, int m,
        unsigned* __restrict__ bar,
        unsigned long long* __restrict__ rec, unsigned* __restrict__ bitmap,
        uint4* __restrict__ Epack, unsigned* __restrict__ bTot,
        float* __restrict__ fTot, uint2* __restrict__ skey2,
        unsigned* __restrict__ sidx, float* __restrict__ xh,
        double* __restrict__ accum, float* __restrict__ out)
{
  constexpr int TOT = GRID * BLK;
  constexpr int BPB = NBUCK / GRID;   // positions per block in scan phase
  constexpr int BPT = BPB / BLK;      // buckets per thread (2 @GRID=1024)
  const int t = threadIdx.x;
  const int g = blockIdx.x;
  const int gtid = g * BLK + t;

  __shared__ unsigned su[BLK];
  __shared__ float    sff[BLK];
  __shared__ double   sd[BLK];
  __shared__ float    wt[4];

  // -------- P1: histogram (one u64 atomic: count@40 | fixedpoint-exp) -----
  unsigned keyR[2]; float seR[2]; unsigned seqR[2]; unsigned evR[2];
  #pragma unroll
  for (int el = 0; el < 2; ++el) {
    int i = gtid + el * TOT;
    keyR[el] = 0u; seR[el] = 0.f; seqR[el] = 0u; evR[el] = 0u;
    if (i < n) {
      float2 te = yt0[i];
      unsigned key = __float_as_uint(te.x);
      keyR[el] = key;
      evR[el] = (te.y != 0.f) ? 0x80000000u : 0u;
      float e = expf(yp0[i]);
      seR[el] = e;
      unsigned long long qe = (unsigned long long)(e * 16777216.0f + 0.5f);
      if (qe > (1ull << 32)) qe = (1ull << 32);   // distribution safety clamp
      unsigned long long ret =
          atomicAdd(&rec[key >> BSHIFT], (1ull << 40) | qe);
      seqR[el] = (unsigned)(ret >> 40);
    }
  }
  for (int j = gtid; j < m; j += TOT) {           // Hj rank bitmap
    int h = Hj[j];
    atomicOr(&bitmap[h >> 5], 1u << (h & 31));
  }
  gbar<GRID>(bar, 1);

  // -------- P2a: bucket {cnt,exp} totals + in-block suffix prefix ---------
  unsigned cK[BPT]; float fK[BPT];
  unsigned thrC; float thrF;
  {
    unsigned runc = 0u; float runf = 0.f;
    #pragma unroll
    for (int k = 0; k < BPT; ++k) {
      int b = NBUCK - 1 - (g * BPB + t * BPT + k);   // descending buckets
      unsigned long long v = rec[b];
      cK[k] = (unsigned)(v >> 40);
      fK[k] = (float)((double)(v & M40) * (1.0 / 16777216.0));
      runc += cK[k]; runf += fK[k];
    }
    su[t] = runc; sff[t] = runf;
    __syncthreads();
    for (int off2 = 1; off2 < BLK; off2 <<= 1) {   // inclusive Hillis-Steele
      unsigned uc = (t >= off2) ? su[t - off2] : 0u;
      float    uf = (t >= off2) ? sff[t - off2] : 0.f;
      __syncthreads();
      su[t] += uc; sff[t] += uf;
      __syncthreads();
    }
    thrC = (t > 0) ? su[t - 1] : 0u;
    thrF = (t > 0) ? sff[t - 1] : 0.f;
    if (t == BLK - 1) { STORE_U32(&bTot[g], su[t]); STORE_F32(&fTot[g], sff[t]); }
  }
  gbar<GRID>(bar, 2);

  // -------- P2b: block bases + write Epack (exclusive suffix per bucket) --
  {
    unsigned partC = 0u; float partF = 0.f;
    for (int j = t; j < g; j += BLK) { partC += bTot[j]; partF += fTot[j]; }
    su[t] = partC; sff[t] = partF;
    __syncthreads();
    for (int s = BLK / 2; s > 0; s >>= 1) {
      if (t < s) { su[t] += su[t + s]; sff[t] += sff[t + s]; }
      __syncthreads();
    }
    unsigned baseC = su[0]; float baseF = sff[0];
    __syncthreads();
    unsigned preC = 0u; float preF = 0.f;
    #pragma unroll
    for (int k = 0; k < BPT; ++k) {
      int b = NBUCK - 1 - (g * BPB + t * BPT + k);
      unsigned sfxC = baseC + thrC + preC;
      float    sfxF = baseF + thrF + preF;
      unsigned long long w =
          ((unsigned long long)__float_as_uint(sfxF) << 32) | sfxC;
      STORE_U64(&Epack[b].x, w);
      STORE_U32(&Epack[b].z, cK[k]);
      preC += cK[k]; preF += fK[k];
    }
  }
  gbar<GRID>(bar, 3);

  // -------- P3: scatter (key/ev/e/ticket from registers) ------------------
  #pragma unroll
  for (int el = 0; el < 2; ++el) {
    int i = gtid + el * TOT;
    if (i < n) {
      unsigned key = keyR[el];
      unsigned b = key >> BSHIFT;
      unsigned start = Epack[b].x;
      unsigned pos = start + seqR[el];
      unsigned long long v =
          ((unsigned long long)__float_as_uint(seR[el]) << 32) | key;
      STORE_U64(&skey2[pos], v);
      STORE_U32(&sidx[pos], (unsigned)i | evR[el]);
    }
  }
  gbar<GRID>(bar, 4);

  // -------- P5: main (rank + denom + lossA + xh scatter), by orig index ---
  {
    double contrib = 0.0;
    #pragma unroll
    for (int el = 0; el < 2; ++el) {
      int i = gtid + el * TOT;
      if (i >= n) continue;
      unsigned key = keyR[el];
      float e = seR[el];
      unsigned idx = (unsigned)i;
      bool evb = evR[el] != 0u;
      unsigned b = key >> BSHIFT;
      uint4 ep = Epack[b];
      unsigned start = ep.x;
      float cross = __uint_as_float(ep.y);
      unsigned end = start + ep.z;
      if (end > (unsigned)n) end = (unsigned)n;    // defensive clamps
      if (start > end) start = end;
      float wsum = 0.f;
      unsigned wcnt = 0u;
      unsigned q = start;
      while (q + 8 <= end) {                        // 8x batched MLP loads
        uint2 v[8];
        #pragma unroll
        for (int k = 0; k < 8; ++k) v[k] = skey2[q + k];
        #pragma unroll
        for (int k = 0; k < 8; ++k) {
          if (v[k].x > key) { wsum += __uint_as_float(v[k].y); wcnt++; }
          else if (v[k].x == key && (sidx[q + k] & 0x7FFFFFFFu) < idx) {
            wsum += __uint_as_float(v[k].y); wcnt++;
          }
        }
        q += 8;
      }
      for (; q < end; ++q) {
        uint2 v = skey2[q];
        if (v.x > key) { wsum += __uint_as_float(v.y); wcnt++; }
        else if (v.x == key && (sidx[q] & 0x7FFFFFFFu) < idx) {
          wsum += __uint_as_float(v.y); wcnt++;
        }
      }
      float denom = cross + wsum + e;
      int rank = (int)(start + wcnt);
      if (evb) contrib += (double)logf(denom / e);
      if ((bitmap[rank >> 5] >> (rank & 31)) & 1u) {   // ~3% of elements
        int lo = 0, hi = m;
        while (lo < hi) { int mid = (lo + hi) >> 1; if (Hj[mid] < rank) lo = mid + 1; else hi = mid; }
        if (lo < m && Hj[lo] == rank) {
          float xb1 = yp1[idx];
          for (int j = lo; j < m && Hj[j] == rank; ++j) STORE_F32(&xh[j], xb1);
        }
      }
    }
    sd[t] = contrib;
    __syncthreads();
    for (int s = 128; s > 0; s >>= 1) { if (t < s) sd[t] += sd[t + s]; __syncthreads(); }
    if (t == 0) atomicAdd(accum, sd[0]);
  }
  gbar<GRID>(bar, 5);

  // -------- P6: cost2 + combine (block 0 only) ----------------------------
  if (g != 0) return;
  {
    int lane = t & 63;
    int w = t >> 6;
    double acc = 0.0;
    float carry = 0.f;
    int passes = (m + 2047) / 2048;      // 4 for m=8192 (256 thr x 8 elem)
    for (int pss = passes - 1; pss >= 0; --pss) {
      int base = pss * 2048 + t * 8;
      float x[8], eb[8];
      float c = 0.f;
      #pragma unroll
      for (int k = 0; k < 8; ++k) {
        int j = base + k;
        x[k] = (j < m) ? xh[j] : 0.f;
        eb[k] = (j < m) ? expf(-x[k]) : 0.f;
        c += eb[k];
      }
      float s = c;
      #pragma unroll
      for (int d = 1; d < 64; d <<= 1) {
        float o = __shfl_down(s, d, 64);
        if (lane + d < 64) s += o;
      }
      float wtot = __shfl(s, 0, 64);
      if (lane == 0) wt[w] = wtot;
      __syncthreads();
      float after = 0.f, ptot = 0.f;
      #pragma unroll
      for (int w2 = 0; w2 < 4; ++w2) { ptot += wt[w2]; if (w2 > w) after += wt[w2]; }
      float S = (s - c) + after + carry;
      #pragma unroll
      for (int k = 7; k >= 0; --k) {
        int j = base + k;
        S += eb[k];
        if (j < m) acc += (double)(expf(x[k]) * S);
      }
      __syncthreads();
      carry += ptot;
    }
    sd[t] = acc;
    __syncthreads();
    for (int s2 = 128; s2 > 0; s2 >>= 1) { if (t < s2) sd[t] += sd[t + s2]; __syncthreads(); }
    if (t == 0) {
      double T = (double)m * (double)(m + 1) * 0.5;
      double cost2 = T - sd[0];
      float lv0 = lv[0], lv1 = lv[1];
      float prec1 = fminf(expf(-lv1), 1.0f);
      double loss = *accum + (double)n * (double)lv0 + (double)prec1 * cost2 + (double)lv1;
      out[0] = (float)loss;
    }
  }
}

extern "C" void kernel_launch(void* const* d_in, const int* in_sizes, int n_in,
                              void* d_out, int out_size, void* d_ws, size_t ws_size,
                              hipStream_t stream) {
  (void)n_in; (void)out_size;
  const float2* yt0 = (const float2*)d_in[0];
  const float*  yp0 = (const float*)d_in[2];
  const float*  yp1 = (const float*)d_in[3];
  const int*    Hj  = (const int*)d_in[4];
  const float*  lv  = (const float*)d_in[5];
  int n = in_sizes[0] / 2;   // y_true0 is [N,2]
  int m = in_sizes[4];

  char* ws = (char*)d_ws;
  unsigned* bar   = (unsigned*)ws;            // 8 KB barrier state (zeroed)
  double*   accum = (double*)(ws + 6144);     // own line inside zeroed region
  size_t off = 8192;
  auto alloc = [&](size_t bytes) -> void* {
    void* p = ws + off;
    off += (bytes + 255) & ~(size_t)255;
    return p;
  };
  size_t nbm = ((size_t)(n + 31) / 32) * 4;                      // rank bitmap
  unsigned* bitmap = (unsigned*)alloc(nbm);                      // zeroed
  unsigned long long* rec = (unsigned long long*)alloc((size_t)NBUCK * 8); // 4MB zeroed
  size_t zbytes = off;                         // bar+bitmap+rec must be zero
  uint4*    Epack = (uint4*)alloc((size_t)NBUCK * 16);           // 8 MB
  unsigned* bTot  = (unsigned*)alloc(1024 * 4);
  float*    fTot  = (float*)alloc(1024 * 4);
  uint2*    skey2 = (uint2*)alloc((size_t)n * 8);
  unsigned* sidx  = (unsigned*)alloc((size_t)n * 4);
  float*    xh    = (float*)alloc((size_t)m * 4);
  if (off > ws_size) return;

  hipMemsetAsync(ws, 0, zbytes, stream);

  // Regular launch (graph-capturable). Co-residency by construction:
  // __launch_bounds__(256,4), low VGPR, ~4.3KB LDS -> 4 blocks/CU; grid 1024
  // = 4 * 256 CUs. Spin guard in gbar is the failsafe.
  static int gridChoice = 0;
  if (gridChoice == 0) {
    int nb = 0;
    hipError_t e1 = hipOccupancyMaxActiveBlocksPerMultiprocessor(&nb, k_fused<1024>, BLK, 0);
    int dev = 0; hipGetDevice(&dev);
    hipDeviceProp_t prop;
    hipError_t e2 = hipGetDeviceProperties(&prop, dev);
    gridChoice = (e1 == hipSuccess && e2 == hipSuccess &&
                  nb * prop.multiProcessorCount >= 1024) ? 1024 : 512;
  }
  if (gridChoice == 1024)
    k_fused<1024><<<dim3(1024), dim3(BLK), 0, stream>>>(
        yt0, yp0, yp1, Hj, lv, n, m, bar, rec, bitmap, Epack, bTot, fTot,
        skey2, sidx, xh, accum, (float*)d_out);
  else
    k_fused<512><<<dim3(512), dim3(BLK), 0, stream>>>(
        yt0, yp0, yp1, Hj, lv, n, m, bar, rec, bitmap, Epack, bTot, fTot,
        skey2, sidx, xh, accum, (float*)d_out);
}

// Round 5
// 138.330 us; speedup vs baseline: 1.1224x; 1.1224x over previous
//
#include <hip/hip_runtime.h>
#include <math.h>

// Round 16: 5-barrier fused pipeline — R15's u64-rec innovation + R14's
// scattered-order P5 locality + compact 8B/bucket Epack + de-serialized barrier.
// R15 post-mortem: regression was traffic (+36MB: 16B Epack, original-order P5
// losing L1-broadcast walks), not the barrier-count reduction.
//   - rec[b] (u64 atomic): cnt<<40 | round(exp(xbeta)*2^24). Deterministic.
//   - Epack[b] (u64, fresh buffer): crossF<<32 | S  (S = # elems in buckets>b).
//     end of bucket region = S[b-1] (adjacent entry), no cnt stored.
//   - P5 iterates SCATTERED positions: wave lanes share a bucket -> walk loads
//     broadcast from L1, uniform trip counts. (R14-verified pattern.)
//   - Barrier v3: arrival RMW on c1[grp] (32 parallel lines) -> group-last
//     STOREs flag[grp] -> block0 lanes 0..31 poll flags in parallel ->
//     32 release slots -> leaders poll own slot. No serialized RMW chain.
// Invariant preserved everywhere: no plain read of a location before its
// in-kernel write; all cross-barrier producer writes are agent-scope relaxed
// stores to fresh buffers (sc1 -> coherent point). Verified pattern (R13-R15).

#define BSHIFT 12
#define NBUCK (1 << 19)          // key>>12 of positive floats
#define BLK 256
#define NC1 32
#define M40 ((1ull << 40) - 1)

#define STORE_U32(p, v) __hip_atomic_store((p), (v), __ATOMIC_RELAXED, __HIP_MEMORY_SCOPE_AGENT)
#define STORE_F32(p, v) __hip_atomic_store((p), (v), __ATOMIC_RELAXED, __HIP_MEMORY_SCOPE_AGENT)
#define STORE_U64(p, v) __hip_atomic_store((unsigned long long*)(p), (v), __ATOMIC_RELAXED, __HIP_MEMORY_SCOPE_AGENT)
#define LOAD_U32(p) __hip_atomic_load((p), __ATOMIC_RELAXED, __HIP_MEMORY_SCOPE_AGENT)

// bar u32 layout: c1[i] @ i*16 (i<32, 64B pad); flag[i] @ 512+i*16;
// rel[i] @ 1024+i*16. Monotonic; zeroed by host memset each launch.
template <int GRID>
__device__ __forceinline__ void gbar(unsigned* bar, unsigned gv) {
  __syncthreads();   // block done; compiler drains vm/lgkm before s_barrier
  constexpr unsigned BPC = GRID / NC1;
  const int t = threadIdx.x;
  const unsigned grp = blockIdx.x & (NC1 - 1);
  if (blockIdx.x == 0) {
    if (t == 0) {
      unsigned a = __hip_atomic_fetch_add(bar + grp * 16, 1u,
                                          __ATOMIC_RELAXED, __HIP_MEMORY_SCOPE_AGENT);
      if (a == gv * BPC - 1u) STORE_U32(bar + 512 + grp * 16, gv);
    }
    if (t < NC1) {                      // 32 parallel pollers (wave 0)
      int guard = 0;
      while (LOAD_U32(bar + 512 + t * 16) < gv) {
        __builtin_amdgcn_s_sleep(1);
        if (++guard > 5000000) break;   // failsafe: never hang the queue
      }
      STORE_U32(bar + 1024 + t * 16, gv);   // release slot for group t
    }
    __syncthreads();
  } else {
    if (t == 0) {
      unsigned a = __hip_atomic_fetch_add(bar + grp * 16, 1u,
                                          __ATOMIC_RELAXED, __HIP_MEMORY_SCOPE_AGENT);
      if (a == gv * BPC - 1u) STORE_U32(bar + 512 + grp * 16, gv);
      int guard = 0;
      while (LOAD_U32(bar + 1024 + grp * 16) < gv) {
        __builtin_amdgcn_s_sleep(1);
        if (++guard > 5000000) break;
      }
    }
    __syncthreads();
  }
}

template <int GRID>
__global__ void __launch_bounds__(BLK, 4)
k_fused(const float2* __restrict__ yt0, const float* __restrict__ yp0,
        const float* __restrict__ yp1, const int* __restrict__ Hj,
        const float* __restrict__ lv, int n, int m,
        unsigned* __restrict__ bar,
        unsigned long long* __restrict__ rec, unsigned* __restrict__ bitmap,
        unsigned long long* __restrict__ Epack, unsigned* __restrict__ bTot,
        float* __restrict__ fTot, uint2* __restrict__ skey2,
        unsigned* __restrict__ sidx, float* __restrict__ xh,
        double* __restrict__ accum, float* __restrict__ out)
{
  constexpr int TOT = GRID * BLK;
  constexpr int BPB = NBUCK / GRID;   // buckets per block in scan phases
  constexpr int BPT = BPB / BLK;      // buckets per thread (2 @GRID=1024)
  const int t = threadIdx.x;
  const int g = blockIdx.x;
  const int gtid = g * BLK + t;

  __shared__ unsigned su[BLK];
  __shared__ float    sff[BLK];
  __shared__ double   sd[BLK];
  __shared__ float    wt[4];

  // -------- P1: histogram (one u64 atomic: count@40 | fixedpoint-exp) -----
  unsigned keyR[2]; float seR[2]; unsigned seqR[2]; unsigned evR[2];
  #pragma unroll
  for (int el = 0; el < 2; ++el) {
    int i = gtid + el * TOT;
    keyR[el] = 0u; seR[el] = 0.f; seqR[el] = 0u; evR[el] = 0u;
    if (i < n) {
      float2 te = yt0[i];
      unsigned key = __float_as_uint(te.x);
      keyR[el] = key;
      evR[el] = (te.y != 0.f) ? 0x80000000u : 0u;
      float e = expf(yp0[i]);
      seR[el] = e;
      unsigned long long qe = (unsigned long long)(e * 16777216.0f + 0.5f);
      if (qe > (1ull << 32)) qe = (1ull << 32);   // distribution safety clamp
      unsigned long long ret =
          atomicAdd(&rec[key >> BSHIFT], (1ull << 40) | qe);
      seqR[el] = (unsigned)(ret >> 40);
    }
  }
  for (int j = gtid; j < m; j += TOT) {           // Hj rank bitmap
    int h = Hj[j];
    atomicOr(&bitmap[h >> 5], 1u << (h & 31));
  }
  gbar<GRID>(bar, 1);

  // -------- P2a: bucket {cnt,exp} totals + in-block suffix prefix ---------
  unsigned cK[BPT]; float fK[BPT];
  unsigned thrC; float thrF;
  {
    unsigned runc = 0u; float runf = 0.f;
    #pragma unroll
    for (int k = 0; k < BPT; ++k) {
      int b = NBUCK - 1 - (g * BPB + t * BPT + k);   // descending buckets
      unsigned long long v = rec[b];
      cK[k] = (unsigned)(v >> 40);
      fK[k] = (float)((double)(v & M40) * (1.0 / 16777216.0));
      runc += cK[k]; runf += fK[k];
    }
    su[t] = runc; sff[t] = runf;
    __syncthreads();
    for (int off2 = 1; off2 < BLK; off2 <<= 1) {   // inclusive Hillis-Steele
      unsigned uc = (t >= off2) ? su[t - off2] : 0u;
      float    uf = (t >= off2) ? sff[t - off2] : 0.f;
      __syncthreads();
      su[t] += uc; sff[t] += uf;
      __syncthreads();
    }
    thrC = (t > 0) ? su[t - 1] : 0u;
    thrF = (t > 0) ? sff[t - 1] : 0.f;
    if (t == BLK - 1) { STORE_U32(&bTot[g], su[t]); STORE_F32(&fTot[g], sff[t]); }
  }
  gbar<GRID>(bar, 2);

  // -------- P2b: block bases + write Epack[b] = crossF<<32 | S ------------
  {
    unsigned partC = 0u; float partF = 0.f;
    for (int j = t; j < g; j += BLK) { partC += bTot[j]; partF += fTot[j]; }
    su[t] = partC; sff[t] = partF;
    __syncthreads();
    for (int s = BLK / 2; s > 0; s >>= 1) {
      if (t < s) { su[t] += su[t + s]; sff[t] += sff[t + s]; }
      __syncthreads();
    }
    unsigned baseC = su[0]; float baseF = sff[0];
    __syncthreads();
    unsigned preC = 0u; float preF = 0.f;
    #pragma unroll
    for (int k = 0; k < BPT; ++k) {
      int b = NBUCK - 1 - (g * BPB + t * BPT + k);
      unsigned sfxC = baseC + thrC + preC;          // S[b]
      float    sfxF = baseF + thrF + preF;          // crossF[b]
      unsigned long long w =
          ((unsigned long long)__float_as_uint(sfxF) << 32) | sfxC;
      STORE_U64(&Epack[b], w);
      preC += cK[k]; preF += fK[k];
    }
  }
  gbar<GRID>(bar, 3);

  // -------- P3: scatter (key/ev/e/ticket from registers; 4B S gather) -----
  #pragma unroll
  for (int el = 0; el < 2; ++el) {
    int i = gtid + el * TOT;
    if (i < n) {
      unsigned key = keyR[el];
      unsigned b = key >> BSHIFT;
      unsigned start = ((const unsigned*)Epack)[2u * b];   // low word = S[b]
      unsigned pos = start + seqR[el];
      unsigned long long v =
          ((unsigned long long)__float_as_uint(seR[el]) << 32) | key;
      STORE_U64(&skey2[pos], v);
      STORE_U32(&sidx[pos], (unsigned)i | evR[el]);
    }
  }
  gbar<GRID>(bar, 4);

  // -------- P5: main in SCATTERED order (lanes share bucket -> L1 walks) --
  {
    double contrib = 0.0;
    #pragma unroll
    for (int el = 0; el < 2; ++el) {
      int p = gtid + el * TOT;
      if (p >= n) continue;
      uint2 kv = skey2[p];                 // coalesced reload
      unsigned key = kv.x;
      float e = __uint_as_float(kv.y);
      unsigned sidv = sidx[p];
      unsigned idx = sidv & 0x7FFFFFFFu;
      bool evb = (sidv >> 31) != 0u;
      unsigned b = key >> BSHIFT;
      unsigned long long ep = Epack[b];
      unsigned start = (unsigned)ep;
      float cross = __uint_as_float((unsigned)(ep >> 32));
      unsigned end = (b > 0) ? ((const unsigned*)Epack)[2u * (b - 1)]
                             : (unsigned)n;          // S[b-1] = end of bucket
      if (end > (unsigned)n) end = (unsigned)n;      // defensive clamps
      if (start > end) start = end;
      float wsum = 0.f;
      unsigned wcnt = 0u;
      unsigned q = start;
      while (q + 8 <= end) {                         // 8x batched MLP loads
        uint2 v[8];
        #pragma unroll
        for (int k = 0; k < 8; ++k) v[k] = skey2[q + k];
        #pragma unroll
        for (int k = 0; k < 8; ++k) {
          if (v[k].x > key) { wsum += __uint_as_float(v[k].y); wcnt++; }
          else if (v[k].x == key && (sidx[q + k] & 0x7FFFFFFFu) < idx) {
            wsum += __uint_as_float(v[k].y); wcnt++;
          }
        }
        q += 8;
      }
      for (; q < end; ++q) {
        uint2 v = skey2[q];
        if (v.x > key) { wsum += __uint_as_float(v.y); wcnt++; }
        else if (v.x == key && (sidx[q] & 0x7FFFFFFFu) < idx) {
          wsum += __uint_as_float(v.y); wcnt++;
        }
      }
      float denom = cross + wsum + e;
      int rank = (int)(start + wcnt);
      if (evb) contrib += (double)logf(denom / e);
      if ((bitmap[rank >> 5] >> (rank & 31)) & 1u) {   // ~3% of elements
        int lo = 0, hi = m;
        while (lo < hi) { int mid = (lo + hi) >> 1; if (Hj[mid] < rank) lo = mid + 1; else hi = mid; }
        if (lo < m && Hj[lo] == rank) {
          float xb1 = yp1[idx];
          for (int j = lo; j < m && Hj[j] == rank; ++j) STORE_F32(&xh[j], xb1);
        }
      }
    }
    sd[t] = contrib;
    __syncthreads();
    for (int s = 128; s > 0; s >>= 1) { if (t < s) sd[t] += sd[t + s]; __syncthreads(); }
    if (t == 0) atomicAdd(accum, sd[0]);
  }
  gbar<GRID>(bar, 5);

  // -------- P6: cost2 + combine (block 0 only) ----------------------------
  if (g != 0) return;
  {
    int lane = t & 63;
    int w = t >> 6;
    double acc = 0.0;
    float carry = 0.f;
    int passes = (m + 2047) / 2048;      // 4 for m=8192 (256 thr x 8 elem)
    for (int pss = passes - 1; pss >= 0; --pss) {
      int base = pss * 2048 + t * 8;
      float x[8], eb[8];
      float c = 0.f;
      #pragma unroll
      for (int k = 0; k < 8; ++k) {
        int j = base + k;
        x[k] = (j < m) ? xh[j] : 0.f;
        eb[k] = (j < m) ? expf(-x[k]) : 0.f;
        c += eb[k];
      }
      float s = c;
      #pragma unroll
      for (int d = 1; d < 64; d <<= 1) {
        float o = __shfl_down(s, d, 64);
        if (lane + d < 64) s += o;
      }
      float wtot = __shfl(s, 0, 64);
      if (lane == 0) wt[w] = wtot;
      __syncthreads();
      float after = 0.f, ptot = 0.f;
      #pragma unroll
      for (int w2 = 0; w2 < 4; ++w2) { ptot += wt[w2]; if (w2 > w) after += wt[w2]; }
      float S = (s - c) + after + carry;
      #pragma unroll
      for (int k = 7; k >= 0; --k) {
        int j = base + k;
        S += eb[k];
        if (j < m) acc += (double)(expf(x[k]) * S);
      }
      __syncthreads();
      carry += ptot;
    }
    sd[t] = acc;
    __syncthreads();
    for (int s2 = 128; s2 > 0; s2 >>= 1) { if (t < s2) sd[t] += sd[t + s2]; __syncthreads(); }
    if (t == 0) {
      double T = (double)m * (double)(m + 1) * 0.5;
      double cost2 = T - sd[0];
      float lv0 = lv[0], lv1 = lv[1];
      float prec1 = fminf(expf(-lv1), 1.0f);
      double loss = *accum + (double)n * (double)lv0 + (double)prec1 * cost2 + (double)lv1;
      out[0] = (float)loss;
    }
  }
}

extern "C" void kernel_launch(void* const* d_in, const int* in_sizes, int n_in,
                              void* d_out, int out_size, void* d_ws, size_t ws_size,
                              hipStream_t stream) {
  (void)n_in; (void)out_size;
  const float2* yt0 = (const float2*)d_in[0];
  const float*  yp0 = (const float*)d_in[2];
  const float*  yp1 = (const float*)d_in[3];
  const int*    Hj  = (const int*)d_in[4];
  const float*  lv  = (const float*)d_in[5];
  int n = in_sizes[0] / 2;   // y_true0 is [N,2]
  int m = in_sizes[4];

  char* ws = (char*)d_ws;
  unsigned* bar   = (unsigned*)ws;            // 8 KB barrier state (zeroed)
  double*   accum = (double*)(ws + 7168);     // own line inside zeroed region
  size_t off = 8192;
  auto alloc = [&](size_t bytes) -> void* {
    void* p = ws + off;
    off += (bytes + 255) & ~(size_t)255;
    return p;
  };
  size_t nbm = ((size_t)(n + 31) / 32) * 4;                      // rank bitmap
  unsigned* bitmap = (unsigned*)alloc(nbm);                      // zeroed
  unsigned long long* rec = (unsigned long long*)alloc((size_t)NBUCK * 8); // 4MB zeroed
  size_t zbytes = off;                         // bar+bitmap+rec must be zero
  unsigned long long* Epack = (unsigned long long*)alloc((size_t)NBUCK * 8); // 4MB
  unsigned* bTot  = (unsigned*)alloc(1024 * 4);
  float*    fTot  = (float*)alloc(1024 * 4);
  uint2*    skey2 = (uint2*)alloc((size_t)n * 8);
  unsigned* sidx  = (unsigned*)alloc((size_t)n * 4);
  float*    xh    = (float*)alloc((size_t)m * 4);
  if (off > ws_size) return;

  hipMemsetAsync(ws, 0, zbytes, stream);

  // Regular launch (graph-capturable). Co-residency by construction:
  // __launch_bounds__(256,4), low VGPR, ~4.2KB LDS -> 4 blocks/CU; grid 1024
  // = 4 * 256 CUs. Spin guards in gbar are the failsafe.
  static int gridChoice = 0;
  if (gridChoice == 0) {
    int nb = 0;
    hipError_t e1 = hipOccupancyMaxActiveBlocksPerMultiprocessor(&nb, k_fused<1024>, BLK, 0);
    int dev = 0; hipGetDevice(&dev);
    hipDeviceProp_t prop;
    hipError_t e2 = hipGetDeviceProperties(&prop, dev);
    gridChoice = (e1 == hipSuccess && e2 == hipSuccess &&
                  nb * prop.multiProcessorCount >= 1024) ? 1024 : 512;
  }
  if (gridChoice == 1024)
    k_fused<1024><<<dim3(1024), dim3(BLK), 0, stream>>>(
        yt0, yp0, yp1, Hj, lv, n, m, bar, rec, bitmap, Epack, bTot, fTot,
        skey2, sidx, xh, accum, (float*)d_out);
  else
    k_fused<512><<<dim3(512), dim3(BLK), 0, stream>>>(
        yt0, yp0, yp1, Hj, lv, n, m, bar, rec, bitmap, Epack, bTot, fTot,
        skey2, sidx, xh, accum, (float*)d_out);
}